// Round 6
// baseline (5964.397 us; speedup 1.0000x reference)
//
#include <hip/hip_runtime.h>
#include <math.h>

typedef __bf16 bf16;
typedef __bf16 bf16x8 __attribute__((ext_vector_type(8)));
typedef __bf16 bf16x4 __attribute__((ext_vector_type(4)));
typedef float  f32x4  __attribute__((ext_vector_type(4)));

#define TT 64
#define DD 768
#define MR 1024      // B*T = 16*64
#define ALPHAF 0.4f
#define NWG 240      // persistent scan workgroups (1 per CU, LDS-limited)

__device__ __forceinline__ float geluf(float x){
  return 0.5f*x*(1.0f + erff(x*0.70710678118654752f));
}
__device__ __forceinline__ void split2(float v, bf16* hi, bf16* lo){
  bf16 h = (bf16)v; *hi = h; *lo = (bf16)(v - (float)h);
}

// ---- coherent (agent-scope, LLC) activation accessors ----
__device__ __forceinline__ unsigned long long ld_a64(const void* p){
  return __hip_atomic_load((const unsigned long long*)p, __ATOMIC_RELAXED, __HIP_MEMORY_SCOPE_AGENT);
}
__device__ __forceinline__ bf16x8 ld_act16(const bf16* p){
  union { unsigned long long u[2]; bf16x8 v; } c;
  c.u[0] = ld_a64(p); c.u[1] = ld_a64(p + 4); return c.v;
}
__device__ __forceinline__ float2 ld_actf2(const float* p){
  union { unsigned long long u; float2 f; } c;
  c.u = ld_a64(p); return c.f;
}
__device__ __forceinline__ float ld_actf(const float* p){
  union { unsigned u; float f; } c;
  c.u = __hip_atomic_load((const unsigned*)p, __ATOMIC_RELAXED, __HIP_MEMORY_SCOPE_AGENT);
  return c.f;
}
__device__ __forceinline__ void st_actf(float* p, float v){
  union { unsigned u; float f; } c; c.f = v;
  __hip_atomic_store((unsigned*)p, c.u, __ATOMIC_RELAXED, __HIP_MEMORY_SCOPE_AGENT);
}
__device__ __forceinline__ void st_actbf(bf16* p, bf16 v){
  union { unsigned short u; bf16 b; } c; c.b = v;
  __hip_atomic_store((unsigned short*)p, c.u, __ATOMIC_RELAXED, __HIP_MEMORY_SCOPE_AGENT);
}
__device__ __forceinline__ void st_act_split(float v, bf16* hi, bf16* lo){
  bf16 h = (bf16)v;
  st_actbf(hi, h);
  st_actbf(lo, (bf16)(v - (float)h));
}

// ---------------- embedding ----------------
__global__ __launch_bounds__(256) void k_embed(const int* __restrict__ tok,
    const float* __restrict__ emb, const float* __restrict__ pos, float* __restrict__ x){
  int m = blockIdx.x; int t = m & 63; int id = tok[m];
  const float* e = emb + (size_t)id*DD;
  const float* p = pos + (size_t)t*DD;
  float* xr = x + (size_t)m*DD;
  for (int j = threadIdx.x; j < DD; j += 256) xr[j] = e[j] + p[j];
}

// ---------------- layernorm (+optional l2norm) ----------------
template<bool L2N>
__global__ __launch_bounds__(256) void k_ln(const float* __restrict__ in,
    const float* __restrict__ g, const float* __restrict__ b, float* __restrict__ out){
  __shared__ float red[8];
  int m = blockIdx.x, tid = threadIdx.x, lane = tid & 63, wid = tid >> 6;
  const float* x = in + (size_t)m*DD;
  float v[3]; float s = 0.f, ss = 0.f;
  #pragma unroll
  for (int j = 0; j < 3; j++){ float t0 = x[tid + j*256]; v[j] = t0; s += t0; ss += t0*t0; }
  #pragma unroll
  for (int o = 1; o < 64; o <<= 1){ s += __shfl_xor(s, o); ss += __shfl_xor(ss, o); }
  if (lane == 0){ red[wid] = s; red[4+wid] = ss; }
  __syncthreads();
  s  = red[0]+red[1]+red[2]+red[3];
  ss = red[4]+red[5]+red[6]+red[7];
  float mean = s*(1.f/768.f);
  float var  = ss*(1.f/768.f) - mean*mean;
  float rstd = rsqrtf(var + 1e-5f);
  float y[3];
  #pragma unroll
  for (int j = 0; j < 3; j++){ int n = tid + j*256; y[j] = (v[j]-mean)*rstd*g[n] + b[n]; }
  if (L2N){
    float n2 = y[0]*y[0] + y[1]*y[1] + y[2]*y[2];
    #pragma unroll
    for (int o = 1; o < 64; o <<= 1) n2 += __shfl_xor(n2, o);
    __syncthreads();
    if (lane == 0) red[wid] = n2;
    __syncthreads();
    n2 = red[0]+red[1]+red[2]+red[3];
    float inv = 1.f / fmaxf(sqrtf(n2), 1e-12f);
    y[0] *= inv; y[1] *= inv; y[2] *= inv;
  }
  float* o_ = out + (size_t)m*DD;
  #pragma unroll
  for (int j = 0; j < 3; j++) o_[tid + j*256] = y[j];
}

// ---------------- attention (one WG per (b,h)) ----------------
__global__ __launch_bounds__(256) void k_attn(const float* __restrict__ qkv, float* __restrict__ o){
  __shared__ float kv[64][96];
  __shared__ float sm[64][68];
  int bh = blockIdx.x; int b = bh >> 3, h = bh & 7;
  int tid = threadIdx.x;
  const float* base = qkv + (size_t)b*64*2304 + h*96;
  for (int idx = tid; idx < 64*96; idx += 256){ int i = idx/96, d = idx - i*96;
    kv[i][d] = base[(size_t)i*2304 + 768 + d]; }
  __syncthreads();
  {
    int i = tid >> 2;
    const float* q = base + (size_t)i*2304;
    int j0 = (tid & 3)*16;
    for (int jj = 0; jj < 16; jj++){
      int j = j0 + jj;
      float sv = -1e30f;
      if (j <= i){ float acc = 0.f;
        for (int d = 0; d < 96; d++) acc += q[d]*kv[j][d];
        sv = acc*0.10206207261596576f; }
      sm[i][j] = sv;
    }
  }
  __syncthreads();
  for (int idx = tid; idx < 64*96; idx += 256){ int i = idx/96, d = idx - i*96;
    kv[i][d] = base[(size_t)i*2304 + 1536 + d]; }
  if (tid < 64){
    int i = tid;
    float mx = -1e30f;
    for (int j = 0; j <= i; j++) mx = fmaxf(mx, sm[i][j]);
    float sum = 0.f;
    for (int j = 0; j <= i; j++){ float e = expf(sm[i][j]-mx); sm[i][j] = e; sum += e; }
    float inv = 1.f/sum;
    for (int j = 0; j <= i; j++) sm[i][j] *= inv;
  }
  __syncthreads();
  for (int idx = tid; idx < 64*96; idx += 256){
    int i = idx/96, d = idx - i*96;
    float acc = 0.f;
    for (int j = 0; j <= i; j++) acc += sm[i][j]*kv[j][d];
    o[(size_t)(b*64+i)*768 + h*96 + d] = acc;
  }
}

// ---------------- generic MFMA GEMM: out[M,N] = act(scale*A[M,K]@B[N,K]^T + bias) + res ----------------
template<bool SPLIT>
__global__ __launch_bounds__(256) void k_gemm(
    const float* __restrict__ A, int lda,
    const float* __restrict__ Bw, int ldb, int nrb,
    int M, int N, int K,
    const float* __restrict__ bias, const float* __restrict__ res,
    float* __restrict__ outF, bf16* __restrict__ outB,
    float scale, int act)
{
  __shared__ bf16 Ash[128][40];
  __shared__ bf16 Bsh[128][40];
  __shared__ bf16 Asl[SPLIT?128:1][40];
  __shared__ bf16 Bsl[SPLIT?128:1][40];
  int tid = threadIdx.x;
  int m0 = blockIdx.y*128, n0 = blockIdx.x*128;
  int lane = tid & 63, wid = tid >> 6;
  int wr = (wid >> 1)*64, wc = (wid & 1)*64;
  int l15 = lane & 15, kb = lane >> 4;
  f32x4 acc[4][4];
  #pragma unroll
  for (int i = 0; i < 4; i++)
    #pragma unroll
    for (int j = 0; j < 4; j++){ f32x4 z = {0.f,0.f,0.f,0.f}; acc[i][j] = z; }
  int rA = tid >> 3;          // 0..31
  int k4 = (tid & 7)*4;       // 0..28
  for (int kk = 0; kk < K; kk += 32){
    #pragma unroll
    for (int it = 0; it < 4; ++it){
      int r = it*32 + rA;
      float4 va = *(const float4*)(A + (size_t)(m0+r)*lda + kk + k4);
      bf16 h0,h1_,h2,h3,l0,l1,l2,l3;
      split2(va.x,&h0,&l0); split2(va.y,&h1_,&l1); split2(va.z,&h2,&l2); split2(va.w,&h3,&l3);
      *(bf16x4*)(&Ash[r][k4]) = (bf16x4){h0,h1_,h2,h3};
      if (SPLIT) *(bf16x4*)(&Asl[r][k4]) = (bf16x4){l0,l1,l2,l3};
      int rB = n0 + r;
      float4 vb;
      if (rB < nrb) vb = *(const float4*)(Bw + (size_t)rB*ldb + kk + k4);
      else { vb.x = 0.f; vb.y = 0.f; vb.z = 0.f; vb.w = 0.f; }
      split2(vb.x,&h0,&l0); split2(vb.y,&h1_,&l1); split2(vb.z,&h2,&l2); split2(vb.w,&h3,&l3);
      *(bf16x4*)(&Bsh[r][k4]) = (bf16x4){h0,h1_,h2,h3};
      if (SPLIT) *(bf16x4*)(&Bsl[r][k4]) = (bf16x4){l0,l1,l2,l3};
    }
    __syncthreads();
    bf16x8 ah[4], bh[4], al[4], bl[4];
    #pragma unroll
    for (int i = 0; i < 4; i++){ ah[i] = *(const bf16x8*)(&Ash[wr + i*16 + l15][kb*8]);
      if (SPLIT) al[i] = *(const bf16x8*)(&Asl[wr + i*16 + l15][kb*8]); }
    #pragma unroll
    for (int j = 0; j < 4; j++){ bh[j] = *(const bf16x8*)(&Bsh[wc + j*16 + l15][kb*8]);
      if (SPLIT) bl[j] = *(const bf16x8*)(&Bsl[wc + j*16 + l15][kb*8]); }
    #pragma unroll
    for (int i = 0; i < 4; i++)
      #pragma unroll
      for (int j = 0; j < 4; j++){
        acc[i][j] = __builtin_amdgcn_mfma_f32_16x16x32_bf16(ah[i], bh[j], acc[i][j], 0, 0, 0);
        if (SPLIT){
          acc[i][j] = __builtin_amdgcn_mfma_f32_16x16x32_bf16(ah[i], bl[j], acc[i][j], 0, 0, 0);
          acc[i][j] = __builtin_amdgcn_mfma_f32_16x16x32_bf16(al[i], bh[j], acc[i][j], 0, 0, 0);
        }
      }
    __syncthreads();
  }
  #pragma unroll
  for (int i = 0; i < 4; i++){
    #pragma unroll
    for (int j = 0; j < 4; j++){
      #pragma unroll
      for (int r = 0; r < 4; r++){
        int m = m0 + wr + i*16 + kb*4 + r;
        int n = n0 + wc + j*16 + l15;
        if (n < N){
          float v = acc[i][j][r]*scale;
          if (bias) v += bias[n];
          if (act == 1) v = geluf(v);
          if (res) v += res[(size_t)m*N + n];
          size_t off = (size_t)m*N + n;
          if (outF) outF[off] = v;
          if (outB) outB[off] = (bf16)v;
        }
      }
    }
  }
}

// ---------------- transpose / split helpers ----------------
__global__ __launch_bounds__(256) void k_transpose_f(const float* __restrict__ in, float* __restrict__ out, int R, int C){
  __shared__ float tile[32][33];
  int r0 = blockIdx.y*32, c0 = blockIdx.x*32;
  int tx = threadIdx.x & 31, ty = threadIdx.x >> 5;
  #pragma unroll
  for (int i = 0; i < 32; i += 8) tile[ty+i][tx] = in[(size_t)(r0+ty+i)*C + (c0+tx)];
  __syncthreads();
  #pragma unroll
  for (int i = 0; i < 32; i += 8) out[(size_t)(c0+ty+i)*R + (r0+tx)] = tile[tx][ty+i];
}

__global__ __launch_bounds__(256) void k_transpose_split(const float* __restrict__ in,
    bf16* __restrict__ hi, bf16* __restrict__ lo, int R, int C){
  __shared__ float tile[32][33];
  int r0 = blockIdx.y*32, c0 = blockIdx.x*32;
  int tx = threadIdx.x & 31, ty = threadIdx.x >> 5;
  #pragma unroll
  for (int i = 0; i < 32; i += 8) tile[ty+i][tx] = in[(size_t)(r0+ty+i)*C + (c0+tx)];
  __syncthreads();
  #pragma unroll
  for (int i = 0; i < 32; i += 8){
    size_t off = (size_t)(c0+ty+i)*R + (r0+tx);
    split2(tile[tx][ty+i], hi+off, lo+off);
  }
}

__global__ __launch_bounds__(256) void k_split(const float* __restrict__ in,
    bf16* __restrict__ hi, bf16* __restrict__ lo, int n){
  int i = blockIdx.x*256 + threadIdx.x;
  if (i < n) split2(in[i], hi+i, lo+i);
}

__global__ __launch_bounds__(256) void k_bdg(const float* __restrict__ gw, const float* __restrict__ cpb2, float* __restrict__ bdg){
  int g = blockIdx.x*256 + threadIdx.x;
  if (g < 768){
    const float* row = gw + (size_t)g*1536 + 768;
    float s = 0.f;
    for (int j = 0; j < 768; j++) s += cpb2[j]*row[j];
    bdg[g] = s;
  }
}

__global__ void k_init(int* flags){
  flags[threadIdx.x] = 0;
}

// ---------------- persistent scan, weights pinned in LDS ----------------
// LDS layout (147456 B):
//   area A  @0      : stage-A slice  [16 rows][768 K] hi (24576) + lo (24576)   (all bids)
//   area 2  @49152  : bid<96  : V1 half   [16][1536] hi (49152) + lo (49152)
//                     96..143 : Wc1       [16][768]  hi (24576) + lo (24576)
//                     144..191: WD fused  [32][768]  hi (49152) + lo (49152)
//                     192..239: (none)
// Row-major, byte ^= (row&7)<<4 swizzle.
template<int NBLK>
__device__ __forceinline__ f32x4 dot_lds(const char* area, int rowBytes, int loOff,
    int row, int kloc, const bf16* ah, const bf16* al){
  f32x4 a0 = {0.f,0.f,0.f,0.f}, a1 = {0.f,0.f,0.f,0.f};
  const int rowoff = row*rowBytes, sw = (row&7)<<4;
  #pragma unroll
  for (int b = 0; b < NBLK; b++){
    int wb = (rowoff + (kloc + b*32)*2) ^ sw;
    bf16x8 vbh = *(const bf16x8*)(area + wb);
    bf16x8 vbl = *(const bf16x8*)(area + loOff + wb);
    bf16x8 vah = ld_act16(ah + b*32);
    bf16x8 val_ = ld_act16(al + b*32);
    a0 = __builtin_amdgcn_mfma_f32_16x16x32_bf16(vah, vbh, a0, 0,0,0);
    a1 = __builtin_amdgcn_mfma_f32_16x16x32_bf16(vah, vbl, a1, 0,0,0);
    a1 = __builtin_amdgcn_mfma_f32_16x16x32_bf16(val_, vbh, a1, 0,0,0);
  }
  return a0 + a1;
}

// conflict-free cross-wave reduce buffers (lane-contiguous b32)
__device__ __forceinline__ void red_store(float* rb, int lane, f32x4 a){
  rb[lane] = a[0]; rb[64+lane] = a[1]; rb[128+lane] = a[2]; rb[192+lane] = a[3];
}
__device__ __forceinline__ f32x4 red_sum4(float rb[4][256], int lane){
  f32x4 s;
  #pragma unroll
  for (int r = 0; r < 4; r++)
    s[r] = rb[0][r*64+lane] + rb[1][r*64+lane] + rb[2][r*64+lane] + rb[3][r*64+lane];
  return s;
}
__device__ __forceinline__ f32x4 red_sum2(float rb[4][256], int lane, int w0, int w1){
  f32x4 s;
  #pragma unroll
  for (int r = 0; r < 4; r++)
    s[r] = rb[w0][r*64+lane] + rb[w1][r*64+lane];
  return s;
}

// packed-flag barrier: flags[bid] (4B stride, 8 LLC lines); wave 0 polls,
// each lane covers 4 flags via two 8B atomic loads.
__device__ __forceinline__ void gbar(int* flags, int ep, int bid){
  asm volatile("s_waitcnt vmcnt(0)" ::: "memory");   // this wave's agent stores at LLC
  __syncthreads();                                   // all waves drained
  if (threadIdx.x == 0)
    __hip_atomic_store(flags + bid, ep, __ATOMIC_RELAXED, __HIP_MEMORY_SCOPE_AGENT);
  if (threadIdx.x < 64){
    const unsigned long long* p = (const unsigned long long*)flags + threadIdx.x*2;
    bool idle = (threadIdx.x >= 60);                 // lanes 60..63 cover flags 240..255 (unused)
    while (true){
      unsigned long long a = ld_a64(p);
      unsigned long long b = ld_a64(p+1);
      bool ok = idle || ((int)a >= ep && (int)(a>>32) >= ep &&
                         (int)b >= ep && (int)(b>>32) >= ep);
      if (__ballot(ok) == ~0ull) break;
      __builtin_amdgcn_s_sleep(1);
    }
  }
  __syncthreads();
}

__global__ __launch_bounds__(256, 1) void k_scan(
  const bf16* __restrict__ WAh, const bf16* __restrict__ WAl,
  const bf16* __restrict__ V1th, const bf16* __restrict__ V1tl,
  const bf16* __restrict__ Wc1h, const bf16* __restrict__ Wc1l,
  const bf16* __restrict__ WDh, const bf16* __restrict__ WDl,
  const float* __restrict__ ctxV0b, const float* __restrict__ gctx,
  const float* __restrict__ ctx,
  const float* __restrict__ b1, const float* __restrict__ cpb1,
  const float* __restrict__ cpb2, const float* __restrict__ bdg,
  const float* __restrict__ gateb, const float* __restrict__ outg, const float* __restrict__ outb,
  float* __restrict__ hall,
  bf16* __restrict__ h1h, bf16* __restrict__ h1l,
  bf16* __restrict__ gcah, bf16* __restrict__ gcal,
  float* __restrict__ tfs, float* __restrict__ pB,
  float* __restrict__ val, float* __restrict__ pp, int* flags)
{
  __shared__ __align__(16) char smem[147456];
  __shared__ float redbuf[4][256];
  __shared__ float normp[4][16];
  const int tid = threadIdx.x, lane = tid & 63, wid = tid >> 6;
  const int bid = blockIdx.x;
  const int l15 = lane & 15, kb = lane >> 4;

  // ---- stage weights into LDS (once) ----
  {
    const bf16* sh = WAh + (size_t)bid*16*768;
    const bf16* sl = WAl + (size_t)bid*16*768;
    for (int c = tid; c < 1536; c += 256){
      int row = c/96, kc = c - row*96;
      int off = (row*1536 + kc*16) ^ ((row&7)<<4);
      *(bf16x8*)(smem + off)         = *(const bf16x8*)(sh + (size_t)row*768 + kc*8);
      *(bf16x8*)(smem + 24576 + off) = *(const bf16x8*)(sl + (size_t)row*768 + kc*8);
    }
    if (bid < 96){
      int u = (bid < 48) ? bid : bid - 48;
      int hk = (bid < 48) ? 0 : 1;
      const bf16* bh_ = V1th + (size_t)u*16*3072 + hk*1536;
      const bf16* bl_ = V1tl + (size_t)u*16*3072 + hk*1536;
      for (int c = tid; c < 3072; c += 256){
        int row = c/192, kc = c - row*192;
        int off = (row*3072 + kc*16) ^ ((row&7)<<4);
        *(bf16x8*)(smem + 49152 + off)         = *(const bf16x8*)(bh_ + (size_t)row*3072 + kc*8);
        *(bf16x8*)(smem + 49152 + 49152 + off) = *(const bf16x8*)(bl_ + (size_t)row*3072 + kc*8);
      }
    } else if (bid < 144){
      const bf16* bh_ = Wc1h + (size_t)(bid-96)*16*768;
      const bf16* bl_ = Wc1l + (size_t)(bid-96)*16*768;
      for (int c = tid; c < 1536; c += 256){
        int row = c/96, kc = c - row*96;
        int off = (row*1536 + kc*16) ^ ((row&7)<<4);
        *(bf16x8*)(smem + 49152 + off)         = *(const bf16x8*)(bh_ + (size_t)row*768 + kc*8);
        *(bf16x8*)(smem + 49152 + 24576 + off) = *(const bf16x8*)(bl_ + (size_t)row*768 + kc*8);
      }
    } else if (bid < 192){
      int u = bid - 144;
      for (int c = tid; c < 3072; c += 256){
        int row = c/96, kc = c - row*96;
        int grow = (row < 16) ? (u*16 + row) : (768 + u*16 + (row - 16));
        int off = (row*1536 + kc*16) ^ ((row&7)<<4);
        *(bf16x8*)(smem + 49152 + off)         = *(const bf16x8*)(WDh + (size_t)grow*768 + kc*8);
        *(bf16x8*)(smem + 49152 + 49152 + off) = *(const bf16x8*)(WDl + (size_t)grow*768 + kc*8);
      }
    }
  }
  __syncthreads();

  int ep = 0;
  for (int t = 0; t < TT; ++t){
    // ==== stage A (all 240 WGs): one 16-col slice of h@WA^T, K=768 split 4 waves.
    // h reconstructed on the fly from val/pp of step t-1 (LN finish, redundant per WG).
    {
      const int kbase = wid*192 + kb*8;
      f32x4 a0 = {0.f,0.f,0.f,0.f};
      if (t > 0){
        float s = 0.f, ss = 0.f;
        {
          int m = lane & 15, q = lane >> 4;
          const float* pq = pp + m*96 + q*24;
          #pragma unroll
          for (int j = 0; j < 12; j++){ float2 v2 = ld_actf2(pq + j*2); s += v2.x; ss += v2.y; }
        }
        s += __shfl_xor(s,16); ss += __shfl_xor(ss,16);
        s += __shfl_xor(s,32); ss += __shfl_xor(ss,32);
        float mean = s*(1.f/768.f);
        float rstd = rsqrtf(ss*(1.f/768.f) - mean*mean + 1e-5f);
        const float* vp  = val + (size_t)l15*768 + kbase;
        const float* gp0 = outg + kbase;
        const float* bp0 = outb + kbase;
        float* hallp = hall + ((size_t)l15*TT + (t-1))*DD + kbase;
        const int rowoff = l15*1536, sw = (l15&7)<<4;
        f32x4 a1 = {0.f,0.f,0.f,0.f};
        #pragma unroll
        for (int b = 0; b < 6; b++){
          float2 e0 = ld_actf2(vp+b*32), e1 = ld_actf2(vp+b*32+2);
          float2 e2 = ld_actf2(vp+b*32+4), e3 = ld_actf2(vp+b*32+6);
          float vv[8] = {e0.x,e0.y,e1.x,e1.y,e2.x,e2.y,e3.x,e3.y};
          bf16x8 ah, al;
          #pragma unroll
          for (int j = 0; j < 8; j++){
            float y = (vv[j]-mean)*rstd*gp0[b*32+j] + bp0[b*32+j];
            y = fminf(5.f, fmaxf(-5.f, y));
            if (bid == 0) hallp[b*32+j] = y;
            bf16 hi = (bf16)y; ah[j] = hi; al[j] = (bf16)(y - (float)hi);
          }
          int wb = (rowoff + (kbase + b*32)*2) ^ sw;
          bf16x8 vbh = *(const bf16x8*)(smem + wb);
          bf16x8 vbl = *(const bf16x8*)(smem + 24576 + wb);
          a0 = __builtin_amdgcn_mfma_f32_16x16x32_bf16(ah, vbh, a0, 0,0,0);
          a1 = __builtin_amdgcn_mfma_f32_16x16x32_bf16(ah, vbl, a1, 0,0,0);
          a1 = __builtin_amdgcn_mfma_f32_16x16x32_bf16(al, vbh, a1, 0,0,0);
        }
        a0 += a1;
      }
      red_store(redbuf[wid], lane, a0);
      __syncthreads();
      if (wid == 0){
        f32x4 s4 = red_sum4(redbuf, lane);
        int n0 = bid*16;
        if (bid < 192){
          #pragma unroll
          for (int r = 0; r < 4; r++){
            int m = kb*4 + r, n = n0 + l15;
            float hv = geluf(s4[r] + ctxV0b[((size_t)m*TT + t)*3072 + n]);
            st_act_split(hv, h1h + m*3072 + n, h1l + m*3072 + n);
          }
        } else {
          #pragma unroll
          for (int r = 0; r < 4; r++){
            int m = kb*4 + r, n = n0 - 3072 + l15;
            st_actf(tfs + m*DD + n, s4[r]);
          }
        }
      }
    }
    gbar(flags, ++ep, bid);
    // ==== stage B (bids 0..95): partial c1-pre = h1 @ V1half -> pB[hk]
    if (bid < 96){
      int hk = (bid >= 48);
      int ka = wid*384 + kb*8;
      const bf16* ahp = h1h + (size_t)l15*3072 + hk*1536 + ka;
      const bf16* alp = h1l + (size_t)l15*3072 + hk*1536 + ka;
      f32x4 a = dot_lds<12>(smem + 49152, 3072, 49152, l15, ka, ahp, alp);
      red_store(redbuf[wid], lane, a);
    }
    __syncthreads();
    if (bid < 96 && wid == 0){
      f32x4 s4 = red_sum4(redbuf, lane);
      int hk = (bid >= 48);
      int n0 = ((bid >= 48) ? bid - 48 : bid)*16;
      #pragma unroll
      for (int r = 0; r < 4; r++){
        int m = kb*4 + r, n = n0 + l15;
        st_actf(pB + hk*12288 + m*768 + n, s4[r]);
      }
    }
    gbar(flags, ++ep, bid);
    // ==== stage C (bids 96..143): c1 = gelu(pB0+pB1+b1) in-register; sumsq fused;
    //      gca = gelu(l2norm(c1) @ cp_w1^T + cp_b1)
    if (bid >= 96 && bid < 144){
      const int k0 = wid*192 + kb*8;
      const float* p0 = pB + (size_t)l15*768 + k0;
      const float* p1 = pB + 12288 + (size_t)l15*768 + k0;
      const float* b1p = b1 + k0;
      const int rowoff = l15*1536, sw = (l15&7)<<4;
      f32x4 a0 = {0.f,0.f,0.f,0.f}, a1 = {0.f,0.f,0.f,0.f};
      float sq = 0.f;
      #pragma unroll
      for (int b = 0; b < 6; b++){
        float2 x0 = ld_actf2(p0+b*32), x1 = ld_actf2(p0+b*32+2);
        float2 x2 = ld_actf2(p0+b*32+4), x3 = ld_actf2(p0+b*32+6);
        float2 y0 = ld_actf2(p1+b*32), y1 = ld_actf2(p1+b*32+2);
        float2 y2 = ld_actf2(p1+b*32+4), y3 = ld_actf2(p1+b*32+6);
        float cc[8] = {x0.x+y0.x, x0.y+y0.y, x1.x+y1.x, x1.y+y1.y,
                       x2.x+y2.x, x2.y+y2.y, x3.x+y3.x, x3.y+y3.y};
        bf16x8 ah, al;
        #pragma unroll
        for (int j = 0; j < 8; j++){
          float cv = geluf(cc[j] + b1p[b*32+j]);
          sq = fmaf(cv, cv, sq);
          bf16 hi = (bf16)cv; ah[j] = hi; al[j] = (bf16)(cv - (float)hi);
        }
        int wb = (rowoff + (k0 + b*32)*2) ^ sw;
        bf16x8 vbh = *(const bf16x8*)(smem + 49152 + wb);
        bf16x8 vbl = *(const bf16x8*)(smem + 49152 + 24576 + wb);
        a0 = __builtin_amdgcn_mfma_f32_16x16x32_bf16(ah, vbh, a0, 0,0,0);
        a1 = __builtin_amdgcn_mfma_f32_16x16x32_bf16(ah, vbl, a1, 0,0,0);
        a1 = __builtin_amdgcn_mfma_f32_16x16x32_bf16(al, vbh, a1, 0,0,0);
      }
      a0 += a1;
      sq += __shfl_xor(sq,16); sq += __shfl_xor(sq,32);
      if (lane < 16) normp[wid][lane] = sq;
      red_store(redbuf[wid], lane, a0);
    }
    __syncthreads();
    if (bid >= 96 && bid < 144 && wid == 0){
      f32x4 s4 = red_sum4(redbuf, lane);
      int n0 = (bid-96)*16;
      #pragma unroll
      for (int r = 0; r < 4; r++){
        int m = kb*4 + r, n = n0 + l15;
        float nm = normp[0][m] + normp[1][m] + normp[2][m] + normp[3][m];
        float inv = 1.f / fmaxf(sqrtf(nm), 1e-12f);
        float v = geluf(s4[r]*inv + cpb1[n]);
        st_act_split(v, gcah + m*DD + n, gcal + m*DD + n);
      }
    }
    gbar(flags, ++ep, bid);
    // ==== stage D (bids 144..191): cf & gpre for 16 cols; val = gate-combine; post partials
    if (bid >= 144 && bid < 192){
      int isg = wid >> 1;            // 0: cf rows (LDS 0..15), 1: gpre rows (LDS 16..31)
      int kh  = wid & 1;             // K half
      int ka  = kh*384 + kb*8;
      const bf16* ahp = gcah + (size_t)l15*DD + ka;
      const bf16* alp = gcal + (size_t)l15*DD + ka;
      f32x4 a = dot_lds<12>(smem + 49152, 1536, 49152, isg*16 + l15, ka, ahp, alp);
      red_store(redbuf[wid], lane, a);
    }
    __syncthreads();
    if (bid >= 144 && bid < 192 && wid == 0){
      int u = bid - 144, n0 = u*16;
      f32x4 acf = red_sum2(redbuf, lane, 0, 1);
      f32x4 agp = red_sum2(redbuf, lane, 2, 3);
      float valr[4];
      #pragma unroll
      for (int r = 0; r < 4; r++){
        int m = kb*4 + r, n = n0 + l15;
        size_t gi_idx = ((size_t)m*TT + t)*DD + n;
        float cfv = acf[r] + cpb2[n];
        float gpv = agp[r] + bdg[n];
        float gi  = gctx[gi_idx] + gpv + gateb[n];
        float gate = 1.f/(1.f + expf(-gi));
        float tf = ld_actf(tfs + m*DD + n);
        float vv = gate*(cfv + tf) + (1.f - gate)*ctx[gi_idx];
        st_actf(val + m*768 + n, vv);
        valr[r] = vv;
      }
      #pragma unroll
      for (int r = 0; r < 4; r++){
        float s = valr[r], ss = valr[r]*valr[r];
        #pragma unroll
        for (int o = 1; o < 16; o <<= 1){ s += __shfl_xor(s, o); ss += __shfl_xor(ss, o); }
        if (l15 == 0){
          int m = kb*4 + r;
          st_actf(pp + m*96 + u*2,     s);
          st_actf(pp + m*96 + u*2 + 1, ss);
        }
      }
    }
    gbar(flags, ++ep, bid);
  }
  // ==== epilogue: hall for t = 63 (bid 0)
  if (bid == 0){
    float s = 0.f, ss = 0.f;
    {
      int m = lane & 15, q = lane >> 4;
      const float* pq = pp + m*96 + q*24;
      #pragma unroll
      for (int j = 0; j < 12; j++){ float2 v2 = ld_actf2(pq + j*2); s += v2.x; ss += v2.y; }
    }
    s += __shfl_xor(s,16); ss += __shfl_xor(ss,16);
    s += __shfl_xor(s,32); ss += __shfl_xor(ss,32);
    float mean = s*(1.f/768.f);
    float rstd = rsqrtf(ss*(1.f/768.f) - mean*mean + 1e-5f);
    const int kbase = wid*192 + kb*8;
    const float* vp = val + (size_t)l15*768 + kbase;
    float* hallp = hall + ((size_t)l15*TT + 63)*DD + kbase;
    #pragma unroll
    for (int b = 0; b < 6; b++){
      float2 e0 = ld_actf2(vp+b*32), e1 = ld_actf2(vp+b*32+2);
      float2 e2 = ld_actf2(vp+b*32+4), e3 = ld_actf2(vp+b*32+6);
      float vv[8] = {e0.x,e0.y,e1.x,e1.y,e2.x,e2.y,e3.x,e3.y};
      #pragma unroll
      for (int j = 0; j < 8; j++){
        float y = (vv[j]-mean)*rstd*outg[kbase+b*32+j] + outb[kbase+b*32+j];
        hallp[b*32+j] = fminf(5.f, fmaxf(-5.f, y));
      }
    }
  }
}

// ---------------- host ----------------
static inline void gemmT(hipStream_t s, bool split, const float* A, int lda, const float* Bw, int ldb, int nrb,
                        int M, int N, int K, const float* bias, const float* res,
                        float* outF, bf16* outB, float scale, int act){
  dim3 g((N + 127)/128, M/128);
  if (split) k_gemm<true><<<g, 256, 0, s>>>(A, lda, Bw, ldb, nrb, M, N, K, bias, res, outF, outB, scale, act);
  else       k_gemm<false><<<g, 256, 0, s>>>(A, lda, Bw, ldb, nrb, M, N, K, bias, res, outF, outB, scale, act);
}

extern "C" void kernel_launch(void* const* d_in, const int* in_sizes, int n_in,
                              void* d_out, int out_size, void* d_ws, size_t ws_size,
                              hipStream_t stream)
{
  (void)in_sizes; (void)n_in; (void)out_size; (void)ws_size;
  const int*   tok = (const int*)d_in[0];
  const float* emb = (const float*)d_in[1];
  const float* pos = (const float*)d_in[2];
  const float* aiw = (const float*)d_in[3];
  const float* aib = (const float*)d_in[4];
  const float* aow = (const float*)d_in[5];
  const float* aob = (const float*)d_in[6];
  const float* fw1 = (const float*)d_in[7];
  const float* fb1 = (const float*)d_in[8];
  const float* fw2 = (const float*)d_in[9];
  const float* fb2 = (const float*)d_in[10];
  const float* n1g = (const float*)d_in[11];
  const float* n1b = (const float*)d_in[12];
  const float* n2g = (const float*)d_in[13];
  const float* n2b = (const float*)d_in[14];
  const float* eng = (const float*)d_in[15];
  const float* enb = (const float*)d_in[16];
  const float* V0  = (const float*)d_in[17];
  const float* b0  = (const float*)d_in[18];
  const float* V1  = (const float*)d_in[19];
  const float* b1  = (const float*)d_in[20];
  const float* cw1 = (const float*)d_in[21];
  const float* cb1 = (const float*)d_in[22];
  const float* cw2 = (const float*)d_in[23];
  const float* cb2 = (const float*)d_in[24];
  const float* gw  = (const float*)d_in[25];
  const float* gb  = (const float*)d_in[26];
  const float* tw  = (const float*)d_in[27];
  const float* Rm  = (const float*)d_in[28];
  const float* og  = (const float*)d_in[29];
  const float* ob  = (const float*)d_in[30];
  const float* lmw = (const float*)d_in[31];
  float* out = (float*)d_out;

  char* base = (char*)d_ws; size_t off = 0;
  auto alloc = [&](size_t bytes)->void*{
    off = (off + 255) & ~(size_t)255; void* p = base + off; off += bytes; return p; };

  float* x     = (float*)alloc((size_t)MR*DD*4);
  float* xn    = (float*)alloc((size_t)MR*DD*4);
  float* qkv   = (float*)alloc((size_t)MR*2304*4);
  float* o_    = (float*)alloc((size_t)MR*DD*4);
  float* mid   = (float*)alloc((size_t)MR*2048*4);
  float* ctx   = (float*)alloc((size_t)MR*DD*4);
  float* V0t   = (float*)alloc((size_t)3072*768*4);
  float* cw2t  = (float*)alloc((size_t)768*768*4);
  float* ctxV0 = (float*)alloc((size_t)MR*3072*4);
  float* gctx  = (float*)alloc((size_t)MR*DD*4);
  float* hall  = (float*)alloc((size_t)MR*DD*4);
  float* WAf   = (float*)alloc((size_t)3840*768*4);
  float* WDg   = (float*)alloc((size_t)768*768*4);
  float* bdg   = (float*)alloc(768*4);
  bf16*  WAh   = (bf16*)alloc((size_t)3840*768*2);
  bf16*  WAl   = (bf16*)alloc((size_t)3840*768*2);
  bf16*  V1th  = (bf16*)alloc((size_t)768*3072*2);
  bf16*  V1tl  = (bf16*)alloc((size_t)768*3072*2);
  bf16*  Wc1h  = (bf16*)alloc((size_t)768*768*2);
  bf16*  Wc1l  = (bf16*)alloc((size_t)768*768*2);
  bf16*  WDh   = (bf16*)alloc((size_t)1536*768*2);
  bf16*  WDl   = (bf16*)alloc((size_t)1536*768*2);
  bf16*  h1h   = (bf16*)alloc((size_t)16*3072*2);
  bf16*  h1l   = (bf16*)alloc((size_t)16*3072*2);
  bf16*  gcah  = (bf16*)alloc((size_t)16*768*2);
  bf16*  gcal  = (bf16*)alloc((size_t)16*768*2);
  float* tfs   = (float*)alloc((size_t)16*768*4);
  float* pB    = (float*)alloc((size_t)2*16*768*4);
  float* val   = (float*)alloc((size_t)16*768*4);
  float* pp    = (float*)alloc((size_t)16*96*4);
  int*   flags = (int*)alloc(1024);

  // ----- encoder -----
  k_embed<<<MR, 256, 0, stream>>>(tok, emb, pos, x);
  for (int l = 0; l < 2; l++){
    k_ln<false><<<MR, 256, 0, stream>>>(x, n1g + l*768, n1b + l*768, xn);
    gemmT(stream, true, xn, 768, aiw + (size_t)l*2304*768, 768, 2304, MR, 2304, 768,
         aib + l*2304, nullptr, qkv, nullptr, 1.f, 0);
    k_attn<<<128, 256, 0, stream>>>(qkv, o_);
    gemmT(stream, true, o_, 768, aow + (size_t)l*768*768, 768, 768, MR, 768, 768,
         aob + l*768, x, x, nullptr, 1.f, 0);
    k_ln<false><<<MR, 256, 0, stream>>>(x, n2g + l*768, n2b + l*768, xn);
    gemmT(stream, true, xn, 768, fw1 + (size_t)l*2048*768, 768, 2048, MR, 2048, 768,
         fb1 + l*2048, nullptr, mid, nullptr, 1.f, 1);
    gemmT(stream, true, mid, 2048, fw2 + (size_t)l*768*2048, 2048, 768, MR, 768, 2048,
         fb2 + l*768, x, x, nullptr, 1.f, 0);
  }
  k_ln<true><<<MR, 256, 0, stream>>>(x, eng, enb, ctx);

  // ----- precompute -----
  k_transpose_f<<<dim3(3072/32, 768/32), 256, 0, stream>>>(V0, V0t, 768, 3072);
  k_transpose_f<<<dim3(768/32, 768/32), 256, 0, stream>>>(cw2, cw2t, 768, 768);
  k_transpose_split<<<dim3(768/32, 3072/32), 256, 0, stream>>>(V1, V1th, V1tl, 3072, 768);
  k_split<<<(768*768 + 255)/256, 256, 0, stream>>>(cw1, Wc1h, Wc1l, 768*768);
  k_split<<<(768*768 + 255)/256, 256, 0, stream>>>(cw2, WDh, WDl, 768*768);
  k_bdg<<<3, 256, 0, stream>>>(gw, cb2, bdg);
  gemmT(stream, true, V0t, 768, Rm, 768, 768, 3072, 768, 768, nullptr, nullptr,
       WAf, nullptr, ALPHAF, 0);
  gemmT(stream, true, tw, 768, Rm, 768, 768, 768, 768, 768, nullptr, nullptr,
       WAf + (size_t)3072*768, nullptr, ALPHAF, 0);
  gemmT(stream, true, ctx, 768, V0t, 768, 3072, MR, 3072, 768, b0, nullptr,
       ctxV0, nullptr, 1.f, 0);
  gemmT(stream, true, ctx, 768, gw, 1536, 768, MR, 768, 768, nullptr, nullptr,
       gctx, nullptr, 1.f, 0);
  gemmT(stream, true, gw + 768, 1536, cw2t, 768, 768, 768, 768, 768, nullptr, nullptr,
       WDg, nullptr, 1.f, 0);
  k_split<<<((3840*768) + 255)/256, 256, 0, stream>>>(WAf, WAh, WAl, 3840*768);
  k_split<<<(768*768 + 255)/256, 256, 0, stream>>>(WDg, WDh + (size_t)768*768, WDl + (size_t)768*768, 768*768);

  // ----- recurrence -----
  k_init<<<1, 256, 0, stream>>>(flags);
  k_scan<<<NWG, 256, 0, stream>>>(WAh, WAl, V1th, V1tl, Wc1h, Wc1l, WDh, WDl,
      ctxV0, gctx, ctx, b1, cb1, cb2, bdg, gb, og, ob, hall,
      h1h, h1l, gcah, gcal, tfs, pB, val, pp, flags);

  // ----- lm head (plain bf16) -----
  gemmT(stream, false, hall, 768, lmw, 768, 50257, MR, 50257, 768, nullptr, nullptr,
       out, nullptr, 1.f, 0);
}

// Round 7
// 3958.448 us; speedup vs baseline: 1.5068x; 1.5068x over previous
//
#include <hip/hip_runtime.h>
#include <math.h>

typedef __bf16 bf16;
typedef _Float16 f16;
typedef f16 f16x8 __attribute__((ext_vector_type(8)));
typedef f16 f16x4 __attribute__((ext_vector_type(4)));
typedef float f32x4 __attribute__((ext_vector_type(4)));

#define TT 64
#define DD 768
#define MR 1024      // B*T = 16*64
#define ALPHAF 0.4f
#define NWG 120      // persistent scan workgroups

__device__ __forceinline__ float geluf(float x){
  return 0.5f*x*(1.0f + erff(x*0.70710678118654752f));
}

// ---- coherent (agent-scope, LLC) activation accessors ----
__device__ __forceinline__ unsigned long long ld_a64(const void* p){
  return __hip_atomic_load((const unsigned long long*)p, __ATOMIC_RELAXED, __HIP_MEMORY_SCOPE_AGENT);
}
__device__ __forceinline__ f16x8 ld_act16h(const f16* p){
  union { unsigned long long u[2]; f16x8 v; } c;
  c.u[0] = ld_a64(p); c.u[1] = ld_a64(p + 4); return c.v;
}
__device__ __forceinline__ float ld_actf(const float* p){
  union { unsigned u; float f; } c;
  c.u = __hip_atomic_load((const unsigned*)p, __ATOMIC_RELAXED, __HIP_MEMORY_SCOPE_AGENT);
  return c.f;
}
__device__ __forceinline__ void st_actf(float* p, float v){
  union { unsigned u; float f; } c; c.f = v;
  __hip_atomic_store((unsigned*)p, c.u, __ATOMIC_RELAXED, __HIP_MEMORY_SCOPE_AGENT);
}
__device__ __forceinline__ void st_acth(f16* p, float v){
  union { unsigned short u; f16 h; } c; c.h = (f16)v;
  __hip_atomic_store((unsigned short*)p, c.u, __ATOMIC_RELAXED, __HIP_MEMORY_SCOPE_AGENT);
}

// ---------------- embedding ----------------
__global__ __launch_bounds__(256) void k_embed(const int* __restrict__ tok,
    const float* __restrict__ emb, const float* __restrict__ pos, float* __restrict__ x){
  int m = blockIdx.x; int t = m & 63; int id = tok[m];
  const float* e = emb + (size_t)id*DD;
  const float* p = pos + (size_t)t*DD;
  float* xr = x + (size_t)m*DD;
  for (int j = threadIdx.x; j < DD; j += 256) xr[j] = e[j] + p[j];
}

// ---------------- layernorm (+optional l2norm) ----------------
template<bool L2N>
__global__ __launch_bounds__(256) void k_ln(const float* __restrict__ in,
    const float* __restrict__ g, const float* __restrict__ b, float* __restrict__ out){
  __shared__ float red[8];
  int m = blockIdx.x, tid = threadIdx.x, lane = tid & 63, wid = tid >> 6;
  const float* x = in + (size_t)m*DD;
  float v[3]; float s = 0.f, ss = 0.f;
  #pragma unroll
  for (int j = 0; j < 3; j++){ float t0 = x[tid + j*256]; v[j] = t0; s += t0; ss += t0*t0; }
  #pragma unroll
  for (int o = 1; o < 64; o <<= 1){ s += __shfl_xor(s, o); ss += __shfl_xor(ss, o); }
  if (lane == 0){ red[wid] = s; red[4+wid] = ss; }
  __syncthreads();
  s  = red[0]+red[1]+red[2]+red[3];
  ss = red[4]+red[5]+red[6]+red[7];
  float mean = s*(1.f/768.f);
  float var  = ss*(1.f/768.f) - mean*mean;
  float rstd = rsqrtf(var + 1e-5f);
  float y[3];
  #pragma unroll
  for (int j = 0; j < 3; j++){ int n = tid + j*256; y[j] = (v[j]-mean)*rstd*g[n] + b[n]; }
  if (L2N){
    float n2 = y[0]*y[0] + y[1]*y[1] + y[2]*y[2];
    #pragma unroll
    for (int o = 1; o < 64; o <<= 1) n2 += __shfl_xor(n2, o);
    __syncthreads();
    if (lane == 0) red[wid] = n2;
    __syncthreads();
    n2 = red[0]+red[1]+red[2]+red[3];
    float inv = 1.f / fmaxf(sqrtf(n2), 1e-12f);
    y[0] *= inv; y[1] *= inv; y[2] *= inv;
  }
  float* o_ = out + (size_t)m*DD;
  #pragma unroll
  for (int j = 0; j < 3; j++) o_[tid + j*256] = y[j];
}

// ---------------- attention (one WG per (b,h)) ----------------
__global__ __launch_bounds__(256) void k_attn(const float* __restrict__ qkv, float* __restrict__ o){
  __shared__ float kv[64][96];
  __shared__ float sm[64][68];
  int bh = blockIdx.x; int b = bh >> 3, h = bh & 7;
  int tid = threadIdx.x;
  const float* base = qkv + (size_t)b*64*2304 + h*96;
  for (int idx = tid; idx < 64*96; idx += 256){ int i = idx/96, d = idx - i*96;
    kv[i][d] = base[(size_t)i*2304 + 768 + d]; }
  __syncthreads();
  {
    int i = tid >> 2;
    const float* q = base + (size_t)i*2304;
    int j0 = (tid & 3)*16;
    for (int jj = 0; jj < 16; jj++){
      int j = j0 + jj;
      float sv = -1e30f;
      if (j <= i){ float acc = 0.f;
        for (int d = 0; d < 96; d++) acc += q[d]*kv[j][d];
        sv = acc*0.10206207261596576f; }
      sm[i][j] = sv;
    }
  }
  __syncthreads();
  for (int idx = tid; idx < 64*96; idx += 256){ int i = idx/96, d = idx - i*96;
    kv[i][d] = base[(size_t)i*2304 + 1536 + d]; }
  if (tid < 64){
    int i = tid;
    float mx = -1e30f;
    for (int j = 0; j <= i; j++) mx = fmaxf(mx, sm[i][j]);
    float sum = 0.f;
    for (int j = 0; j <= i; j++){ float e = expf(sm[i][j]-mx); sm[i][j] = e; sum += e; }
    float inv = 1.f/sum;
    for (int j = 0; j <= i; j++) sm[i][j] *= inv;
  }
  __syncthreads();
  for (int idx = tid; idx < 64*96; idx += 256){
    int i = idx/96, d = idx - i*96;
    float acc = 0.f;
    for (int j = 0; j <= i; j++) acc += sm[i][j]*kv[j][d];
    o[(size_t)(b*64+i)*768 + h*96 + d] = acc;
  }
}

// -------- generic fp16 MFMA GEMM: out[M,N] = act(scale*A[M,K]@B[N,K]^T + bias) + res --------
__global__ __launch_bounds__(256) void k_gemm(
    const float* __restrict__ A, int lda,
    const float* __restrict__ Bw, int ldb, int nrb,
    int M, int N, int K,
    const float* __restrict__ bias, const float* __restrict__ res,
    float* __restrict__ outF, f16* __restrict__ outH,
    float scale, int act)
{
  __shared__ f16 As[128][40];
  __shared__ f16 Bs[128][40];
  int tid = threadIdx.x;
  int m0 = blockIdx.y*128, n0 = blockIdx.x*128;
  int lane = tid & 63, wid = tid >> 6;
  int wr = (wid >> 1)*64, wc = (wid & 1)*64;
  int l15 = lane & 15, kb = lane >> 4;
  f32x4 acc[4][4];
  #pragma unroll
  for (int i = 0; i < 4; i++)
    #pragma unroll
    for (int j = 0; j < 4; j++){ f32x4 z = {0.f,0.f,0.f,0.f}; acc[i][j] = z; }
  int rA = tid >> 3;          // 0..31
  int k4 = (tid & 7)*4;       // 0..28
  for (int kk = 0; kk < K; kk += 32){
    #pragma unroll
    for (int it = 0; it < 4; ++it){
      int r = it*32 + rA;
      float4 va = *(const float4*)(A + (size_t)(m0+r)*lda + kk + k4);
      *(f16x4*)(&As[r][k4]) = (f16x4){(f16)va.x,(f16)va.y,(f16)va.z,(f16)va.w};
      int rB = n0 + r;
      float4 vb;
      if (rB < nrb) vb = *(const float4*)(Bw + (size_t)rB*ldb + kk + k4);
      else { vb.x = 0.f; vb.y = 0.f; vb.z = 0.f; vb.w = 0.f; }
      *(f16x4*)(&Bs[r][k4]) = (f16x4){(f16)vb.x,(f16)vb.y,(f16)vb.z,(f16)vb.w};
    }
    __syncthreads();
    f16x8 af[4], bfv[4];
    #pragma unroll
    for (int i = 0; i < 4; i++) af[i]  = *(const f16x8*)(&As[wr + i*16 + l15][kb*8]);
    #pragma unroll
    for (int j = 0; j < 4; j++) bfv[j] = *(const f16x8*)(&Bs[wc + j*16 + l15][kb*8]);
    #pragma unroll
    for (int i = 0; i < 4; i++)
      #pragma unroll
      for (int j = 0; j < 4; j++)
        acc[i][j] = __builtin_amdgcn_mfma_f32_16x16x32_f16(af[i], bfv[j], acc[i][j], 0, 0, 0);
    __syncthreads();
  }
  #pragma unroll
  for (int i = 0; i < 4; i++){
    #pragma unroll
    for (int j = 0; j < 4; j++){
      #pragma unroll
      for (int r = 0; r < 4; r++){
        int m = m0 + wr + i*16 + kb*4 + r;
        int n = n0 + wc + j*16 + l15;
        if (n < N){
          float v = acc[i][j][r]*scale;
          if (bias) v += bias[n];
          if (act == 1) v = geluf(v);
          if (res) v += res[(size_t)m*N + n];
          size_t off = (size_t)m*N + n;
          if (outF) outF[off] = v;
          if (outH) outH[off] = (f16)v;
        }
      }
    }
  }
}

// ---------------- transpose / cast helpers ----------------
__global__ __launch_bounds__(256) void k_transpose_f(const float* __restrict__ in, float* __restrict__ out, int R, int C){
  __shared__ float tile[32][33];
  int r0 = blockIdx.y*32, c0 = blockIdx.x*32;
  int tx = threadIdx.x & 31, ty = threadIdx.x >> 5;
  #pragma unroll
  for (int i = 0; i < 32; i += 8) tile[ty+i][tx] = in[(size_t)(r0+ty+i)*C + (c0+tx)];
  __syncthreads();
  #pragma unroll
  for (int i = 0; i < 32; i += 8) out[(size_t)(c0+ty+i)*R + (r0+tx)] = tile[tx][ty+i];
}

__global__ __launch_bounds__(256) void k_transpose_h(const float* __restrict__ in, f16* __restrict__ out, int R, int C){
  __shared__ float tile[32][33];
  int r0 = blockIdx.y*32, c0 = blockIdx.x*32;
  int tx = threadIdx.x & 31, ty = threadIdx.x >> 5;
  #pragma unroll
  for (int i = 0; i < 32; i += 8) tile[ty+i][tx] = in[(size_t)(r0+ty+i)*C + (c0+tx)];
  __syncthreads();
  #pragma unroll
  for (int i = 0; i < 32; i += 8) out[(size_t)(c0+ty+i)*R + (r0+tx)] = (f16)tile[tx][ty+i];
}

__global__ __launch_bounds__(256) void k_cast_h(const float* __restrict__ in, f16* __restrict__ out, int n){
  int i = blockIdx.x*256 + threadIdx.x;
  if (i < n) out[i] = (f16)in[i];
}

__global__ __launch_bounds__(256) void k_bdg(const float* __restrict__ gw, const float* __restrict__ cpb2, float* __restrict__ bdg){
  int g = blockIdx.x*256 + threadIdx.x;
  if (g < 768){
    const float* row = gw + (size_t)g*1536 + 768;
    float s = 0.f;
    for (int j = 0; j < 768; j++) s += cpb2[j]*row[j];
    bdg[g] = s;
  }
}

__global__ void k_init(int* flags){
  for (int i = threadIdx.x; i < NWG*32; i += 256) flags[i] = 0;
}

// ---------------- persistent scan (fp16 weights pinned in LDS) ----------------
// 120 WGs. LDS layout:
//   @0      : stage-A slice, 32 rows (= output cols bid*32..+31) x 768 K, f16 (49152 B)
//   @49152  : bid<48  : stage-B unit  16 rows x 3072 K (98304 B)
//             48..71  : stage-C 2 units, 32 rows x 768 K (49152 B)
//             72..119 : stage-D 2 units, 32 rows x 768 K (49152 B)
// rows XOR-swizzled: byte ^= (row&7)<<4.

__device__ __forceinline__ void red_store(float* rb, int lane, f32x4 a){
  rb[lane] = a[0]; rb[64+lane] = a[1]; rb[128+lane] = a[2]; rb[192+lane] = a[3];
}
__device__ __forceinline__ f32x4 red_sum4(float rb[4][256], int lane){
  f32x4 s;
  #pragma unroll
  for (int r = 0; r < 4; r++)
    s[r] = rb[0][r*64+lane] + rb[1][r*64+lane] + rb[2][r*64+lane] + rb[3][r*64+lane];
  return s;
}
__device__ __forceinline__ f32x4 red_sum2(float rb[4][256], int lane, int w0, int w1){
  f32x4 s;
  #pragma unroll
  for (int r = 0; r < 4; r++)
    s[r] = rb[w0][r*64+lane] + rb[w1][r*64+lane];
  return s;
}

// flag-array barrier: per-WG cacheline flags; 256 threads poll 120 flags.
__device__ __forceinline__ void gbar(int* flags, int ep, int bid){
  asm volatile("s_waitcnt vmcnt(0)" ::: "memory");
  __syncthreads();
  if (threadIdx.x == 0)
    __hip_atomic_store(flags + bid*32, ep, __ATOMIC_RELAXED, __HIP_MEMORY_SCOPE_AGENT);
  int id = threadIdx.x;
  bool active = id < NWG;
  const int* fp = flags + id*32;
  while (true){
    int v = active ? __hip_atomic_load(fp, __ATOMIC_RELAXED, __HIP_MEMORY_SCOPE_AGENT) : ep;
    if (__ballot(v >= ep) == ~0ull) break;
    __builtin_amdgcn_s_sleep(1);
  }
  __syncthreads();
}

__global__ __launch_bounds__(256, 1) void k_scan(
  const f16* __restrict__ WAf, const f16* __restrict__ V1tf,
  const f16* __restrict__ Wc1f, const f16* __restrict__ WDf,
  const float* __restrict__ ctxV0b, const float* __restrict__ gctx,
  const float* __restrict__ ctx,
  const float* __restrict__ b1, const float* __restrict__ cpb1,
  const float* __restrict__ cpb2, const float* __restrict__ bdg,
  const float* __restrict__ gateb, const float* __restrict__ outg, const float* __restrict__ outb,
  float* __restrict__ hall, f16* __restrict__ hf,
  f16* __restrict__ h1f, f16* __restrict__ c1f, f16* __restrict__ gcaf,
  float* __restrict__ cf, float* __restrict__ gpre,
  float* __restrict__ tfs, int* flags)
{
  __shared__ __align__(16) char smem[147456];
  __shared__ float redbuf[4][256];
  __shared__ float normp[4][16];
  __shared__ float red[8];
  const int tid = threadIdx.x, lane = tid & 63, wid = tid >> 6;
  const int bid = blockIdx.x;
  const int l15 = lane & 15, kb = lane >> 4;

  // ---- stage weights into LDS (once) ----
  {
    const f16* src = WAf + (size_t)bid*32*768;
    for (int c = tid; c < 3072; c += 256){
      int row = c/96, kc = c - row*96;
      int off = (row*1536 + kc*16) ^ ((row&7)<<4);
      *(f16x8*)(smem + off) = *(const f16x8*)(src + (size_t)row*768 + kc*8);
    }
    if (bid < 48){
      const f16* s2 = V1tf + (size_t)bid*16*3072;
      for (int c = tid; c < 6144; c += 256){
        int row = c/384, kc = c - row*384;
        int off = (row*6144 + kc*16) ^ ((row&7)<<4);
        *(f16x8*)(smem + 49152 + off) = *(const f16x8*)(s2 + (size_t)row*3072 + kc*8);
      }
    } else if (bid < 72){
      const f16* s2 = Wc1f + (size_t)(bid-48)*32*768;
      for (int c = tid; c < 3072; c += 256){
        int row = c/96, kc = c - row*96;
        int off = (row*1536 + kc*16) ^ ((row&7)<<4);
        *(f16x8*)(smem + 49152 + off) = *(const f16x8*)(s2 + (size_t)row*768 + kc*8);
      }
    } else {
      const f16* s2 = WDf + (size_t)(bid-72)*32*768;
      for (int c = tid; c < 3072; c += 256){
        int row = c/96, kc = c - row*96;
        int off = (row*1536 + kc*16) ^ ((row&7)<<4);
        *(f16x8*)(smem + 49152 + off) = *(const f16x8*)(s2 + (size_t)row*768 + kc*8);
      }
    }
  }
  __syncthreads();

  int ep = 0;
  for (int t = 0; t < TT; ++t){
    // ==== stage A (all 120 WGs): 32 output cols of h@WA^T; 2 units x 2 K-half waves
    {
      const int u = wid >> 1, kh = wid & 1;
      const int k0 = kh*384 + kb*8;
      f32x4 a = {0.f,0.f,0.f,0.f};
      if (t > 0){
        const f16* ap = hf + ((size_t)l15*TT + (t-1))*DD + k0;
        const int row = u*16 + l15, rowoff = row*1536, sw = (row&7)<<4;
        #pragma unroll
        for (int b = 0; b < 12; b++){
          int wb = (rowoff + (k0 + b*32)*2) ^ sw;
          f16x8 vb = *(const f16x8*)(smem + wb);
          f16x8 va = ld_act16h(ap + b*32);
          a = __builtin_amdgcn_mfma_f32_16x16x32_f16(va, vb, a, 0,0,0);
        }
      }
      red_store(redbuf[wid], lane, a);
    }
    __syncthreads();
    if ((wid & 1) == 0){
      f32x4 s4 = red_sum2(redbuf, lane, wid, wid+1);
      int n = bid*32 + (wid>>1)*16 + l15;
      #pragma unroll
      for (int r = 0; r < 4; r++){
        int m = kb*4 + r;
        if (n < 3072){
          float hv = geluf(s4[r] + ctxV0b[((size_t)m*TT + t)*3072 + n]);
          st_acth(h1f + (size_t)m*3072 + n, hv);
        } else {
          st_actf(tfs + m*DD + (n - 3072), s4[r]);
        }
      }
    }
    gbar(flags, ++ep, bid);
    // ==== stage B (bids 0..47): c1 = gelu(h1 @ V1 + b1), full K=3072, 4-wave K-split
    if (bid < 48){
      const int k0 = wid*768 + kb*8;
      const f16* ap = h1f + (size_t)l15*3072 + k0;
      const int rowoff = l15*6144, sw = (l15&7)<<4;
      f32x4 a = {0.f,0.f,0.f,0.f};
      #pragma unroll
      for (int b = 0; b < 24; b++){
        int wb = (rowoff + (k0 + b*32)*2) ^ sw;
        f16x8 vb = *(const f16x8*)(smem + 49152 + wb);
        f16x8 va = ld_act16h(ap + b*32);
        a = __builtin_amdgcn_mfma_f32_16x16x32_f16(va, vb, a, 0,0,0);
      }
      red_store(redbuf[wid], lane, a);
    }
    __syncthreads();
    if (bid < 48 && wid == 0){
      f32x4 s4 = red_sum4(redbuf, lane);
      int n = bid*16 + l15;
      #pragma unroll
      for (int r = 0; r < 4; r++){
        int m = kb*4 + r;
        float v = geluf(s4[r] + b1[n]);
        st_acth(c1f + (size_t)m*DD + n, v);
      }
    }
    gbar(flags, ++ep, bid);
    // ==== stage C (bids 48..71): gca = gelu(l2norm(c1)@cp_w1^T + cp_b1); sumsq fused
    if (bid >= 48 && bid < 72){
      const int u = wid >> 1, kh = wid & 1;
      const int k0 = kh*384 + kb*8;
      const f16* ap = c1f + (size_t)l15*DD + k0;
      const int row = u*16 + l15, rowoff = row*1536, sw = (row&7)<<4;
      f32x4 a = {0.f,0.f,0.f,0.f};
      float sq = 0.f;
      #pragma unroll
      for (int b = 0; b < 12; b++){
        int wb = (rowoff + (k0 + b*32)*2) ^ sw;
        f16x8 vb = *(const f16x8*)(smem + 49152 + wb);
        f16x8 va = ld_act16h(ap + b*32);
        a = __builtin_amdgcn_mfma_f32_16x16x32_f16(va, vb, a, 0,0,0);
        #pragma unroll
        for (int j = 0; j < 8; j++){ float xv = (float)va[j]; sq = fmaf(xv, xv, sq); }
      }
      sq += __shfl_xor(sq,16); sq += __shfl_xor(sq,32);
      if (lane < 16) normp[wid][lane] = sq;
      red_store(redbuf[wid], lane, a);
    }
    __syncthreads();
    if (bid >= 48 && bid < 72 && (wid & 1) == 0){
      f32x4 s4 = red_sum2(redbuf, lane, wid, wid+1);
      int unit = (bid-48)*2 + (wid>>1);
      int n = unit*16 + l15;
      #pragma unroll
      for (int r = 0; r < 4; r++){
        int m = kb*4 + r;
        float nm = normp[wid][m] + normp[wid+1][m];
        float inv = 1.f / fmaxf(sqrtf(nm), 1e-12f);
        float v = geluf(s4[r]*inv + cpb1[n]);
        st_acth(gcaf + (size_t)m*DD + n, v);
      }
    }
    gbar(flags, ++ep, bid);
    // ==== stage D (bids 72..119): [cf | gate_pre] = gca @ WD^T (2 units x 2 K-half waves)
    if (bid >= 72){
      const int u = wid >> 1, kh = wid & 1;
      const int k0 = kh*384 + kb*8;
      const f16* ap = gcaf + (size_t)l15*DD + k0;
      const int row = u*16 + l15, rowoff = row*1536, sw = (row&7)<<4;
      f32x4 a = {0.f,0.f,0.f,0.f};
      #pragma unroll
      for (int b = 0; b < 12; b++){
        int wb = (rowoff + (k0 + b*32)*2) ^ sw;
        f16x8 vb = *(const f16x8*)(smem + 49152 + wb);
        f16x8 va = ld_act16h(ap + b*32);
        a = __builtin_amdgcn_mfma_f32_16x16x32_f16(va, vb, a, 0,0,0);
      }
      red_store(redbuf[wid], lane, a);
    }
    __syncthreads();
    if (bid >= 72 && (wid & 1) == 0){
      f32x4 s4 = red_sum2(redbuf, lane, wid, wid+1);
      int unit = (bid-72)*2 + (wid>>1);
      int n = unit*16 + l15;            // 0..1535
      #pragma unroll
      for (int r = 0; r < 4; r++){
        int m = kb*4 + r;
        if (n < 768) st_actf(cf + m*DD + n, s4[r] + cpb2[n]);
        else         st_actf(gpre + m*DD + (n - 768), s4[r] + bdg[n - 768]);
      }
    }
    gbar(flags, ++ep, bid);
    // ==== combine (bids 0..15): gate, h_t = clip(LN(...))
    if (bid < 16){
      int m = bid;
      size_t bidx = ((size_t)m*TT + t)*DD;
      float vals[3]; float s = 0.f, ss = 0.f;
      #pragma unroll
      for (int j = 0; j < 3; j++){
        int n = tid + j*256;
        float gi = gctx[bidx + n] + ld_actf(gpre + m*DD + n) + gateb[n];
        float gate = 1.f/(1.f + expf(-gi));
        float v = gate*(ld_actf(cf + m*DD + n) + ld_actf(tfs + m*DD + n)) + (1.f - gate)*ctx[bidx + n];
        vals[j] = v; s += v; ss += v*v;
      }
      #pragma unroll
      for (int o = 1; o < 64; o <<= 1){ s += __shfl_xor(s, o); ss += __shfl_xor(ss, o); }
      if (lane == 0){ red[wid] = s; red[4+wid] = ss; }
      __syncthreads();
      s  = red[0]+red[1]+red[2]+red[3];
      ss = red[4]+red[5]+red[6]+red[7];
      float mean = s*(1.f/768.f), var = ss*(1.f/768.f) - mean*mean;
      float rstd = rsqrtf(var + 1e-5f);
      #pragma unroll
      for (int j = 0; j < 3; j++){
        int n = tid + j*256;
        float y = (vals[j]-mean)*rstd*outg[n] + outb[n];
        y = fminf(5.f, fmaxf(-5.f, y));
        hall[bidx + n] = y;
        st_acth(hf + bidx + n, y);
      }
    }
    gbar(flags, ++ep, bid);
  }
}

// ---------------- host ----------------
static inline void gemmH(hipStream_t s, const float* A, int lda, const float* Bw, int ldb, int nrb,
                        int M, int N, int K, const float* bias, const float* res,
                        float* outF, f16* outH, float scale, int act){
  dim3 g((N + 127)/128, M/128);
  k_gemm<<<g, 256, 0, s>>>(A, lda, Bw, ldb, nrb, M, N, K, bias, res, outF, outH, scale, act);
}

extern "C" void kernel_launch(void* const* d_in, const int* in_sizes, int n_in,
                              void* d_out, int out_size, void* d_ws, size_t ws_size,
                              hipStream_t stream)
{
  (void)in_sizes; (void)n_in; (void)out_size; (void)ws_size;
  const int*   tok = (const int*)d_in[0];
  const float* emb = (const float*)d_in[1];
  const float* pos = (const float*)d_in[2];
  const float* aiw = (const float*)d_in[3];
  const float* aib = (const float*)d_in[4];
  const float* aow = (const float*)d_in[5];
  const float* aob = (const float*)d_in[6];
  const float* fw1 = (const float*)d_in[7];
  const float* fb1 = (const float*)d_in[8];
  const float* fw2 = (const float*)d_in[9];
  const float* fb2 = (const float*)d_in[10];
  const float* n1g = (const float*)d_in[11];
  const float* n1b = (const float*)d_in[12];
  const float* n2g = (const float*)d_in[13];
  const float* n2b = (const float*)d_in[14];
  const float* eng = (const float*)d_in[15];
  const float* enb = (const float*)d_in[16];
  const float* V0  = (const float*)d_in[17];
  const float* b0  = (const float*)d_in[18];
  const float* V1  = (const float*)d_in[19];
  const float* b1  = (const float*)d_in[20];
  const float* cw1 = (const float*)d_in[21];
  const float* cb1 = (const float*)d_in[22];
  const float* cw2 = (const float*)d_in[23];
  const float* cb2 = (const float*)d_in[24];
  const float* gw  = (const float*)d_in[25];
  const float* gb  = (const float*)d_in[26];
  const float* tw  = (const float*)d_in[27];
  const float* Rm  = (const float*)d_in[28];
  const float* og  = (const float*)d_in[29];
  const float* ob  = (const float*)d_in[30];
  const float* lmw = (const float*)d_in[31];
  float* out = (float*)d_out;

  char* base = (char*)d_ws; size_t off = 0;
  auto alloc = [&](size_t bytes)->void*{
    off = (off + 255) & ~(size_t)255; void* p = base + off; off += bytes; return p; };

  float* x     = (float*)alloc((size_t)MR*DD*4);
  float* xn    = (float*)alloc((size_t)MR*DD*4);
  float* qkv   = (float*)alloc((size_t)MR*2304*4);
  float* o_    = (float*)alloc((size_t)MR*DD*4);
  float* mid   = (float*)alloc((size_t)MR*2048*4);
  float* ctx   = (float*)alloc((size_t)MR*DD*4);
  float* V0t   = (float*)alloc((size_t)3072*768*4);
  float* cw2t  = (float*)alloc((size_t)768*768*4);
  float* ctxV0 = (float*)alloc((size_t)MR*3072*4);
  float* gctx  = (float*)alloc((size_t)MR*DD*4);
  float* hall  = (float*)alloc((size_t)MR*DD*4);
  float* bdg   = (float*)alloc(768*4);
  f16*   WAf   = (f16*)alloc((size_t)3840*768*2);
  f16*   V1tf  = (f16*)alloc((size_t)768*3072*2);
  f16*   Wc1f  = (f16*)alloc((size_t)768*768*2);
  f16*   WDf   = (f16*)alloc((size_t)1536*768*2);
  f16*   hf    = (f16*)alloc((size_t)MR*DD*2);
  f16*   h1f   = (f16*)alloc((size_t)16*3072*2);
  f16*   c1f   = (f16*)alloc((size_t)16*768*2);
  f16*   gcaf  = (f16*)alloc((size_t)16*768*2);
  float* cf    = (float*)alloc((size_t)16*768*4);
  float* gpre  = (float*)alloc((size_t)16*768*4);
  float* tfs   = (float*)alloc((size_t)16*768*4);
  int*   flags = (int*)alloc((size_t)NWG*32*4);

  // ----- encoder -----
  k_embed<<<MR, 256, 0, stream>>>(tok, emb, pos, x);
  for (int l = 0; l < 2; l++){
    k_ln<false><<<MR, 256, 0, stream>>>(x, n1g + l*768, n1b + l*768, xn);
    gemmH(stream, xn, 768, aiw + (size_t)l*2304*768, 768, 2304, MR, 2304, 768,
         aib + l*2304, nullptr, qkv, nullptr, 1.f, 0);
    k_attn<<<128, 256, 0, stream>>>(qkv, o_);
    gemmH(stream, o_, 768, aow + (size_t)l*768*768, 768, 768, MR, 768, 768,
         aob + l*768, x, x, nullptr, 1.f, 0);
    k_ln<false><<<MR, 256, 0, stream>>>(x, n2g + l*768, n2b + l*768, xn);
    gemmH(stream, xn, 768, fw1 + (size_t)l*2048*768, 768, 2048, MR, 2048, 768,
         fb1 + l*2048, nullptr, mid, nullptr, 1.f, 1);
    gemmH(stream, mid, 2048, fw2 + (size_t)l*768*2048, 2048, 768, MR, 768, 2048,
         fb2 + l*768, x, x, nullptr, 1.f, 0);
  }
  k_ln<true><<<MR, 256, 0, stream>>>(x, eng, enb, ctx);

  // ----- precompute -----
  k_transpose_f<<<dim3(3072/32, 768/32), 256, 0, stream>>>(V0, V0t, 768, 3072);
  k_transpose_f<<<dim3(768/32, 768/32), 256, 0, stream>>>(cw2, cw2t, 768, 768);
  k_transpose_h<<<dim3(768/32, 3072/32), 256, 0, stream>>>(V1, V1tf, 3072, 768);
  k_cast_h<<<(768*768 + 255)/256, 256, 0, stream>>>(cw1, Wc1f, 768*768);
  k_cast_h<<<(768*768 + 255)/256, 256, 0, stream>>>(cw2, WDf, 768*768);
  k_bdg<<<3, 256, 0, stream>>>(gw, cb2, bdg);
  // WAf[0:3072][k] = ALPHA*(R@V0)[k][n]
  gemmH(stream, V0t, 768, Rm, 768, 768, 3072, 768, 768, nullptr, nullptr,
       nullptr, WAf, ALPHAF, 0);
  // WAf[3072+j][k] = ALPHA*(R@temp_w^T)[k][j]
  gemmH(stream, tw, 768, Rm, 768, 768, 768, 768, 768, nullptr, nullptr,
       nullptr, WAf + (size_t)3072*768, ALPHAF, 0);
  // ctxV0 = ctx@V0 + b0
  gemmH(stream, ctx, 768, V0t, 768, 3072, MR, 3072, 768, b0, nullptr,
       ctxV0, nullptr, 1.f, 0);
  // gctx = ctx @ gate_w[:, :768]^T
  gemmH(stream, ctx, 768, gw, 1536, 768, MR, 768, 768, nullptr, nullptr,
       gctx, nullptr, 1.f, 0);
  // WDf[768+g][i] = (gate_w[:,768:] @ cp_w2)[g][i]
  gemmH(stream, gw + 768, 1536, cw2t, 768, 768, 768, 768, 768, nullptr, nullptr,
       nullptr, WDf + (size_t)768*768, 1.f, 0);

  // ----- recurrence -----
  k_init<<<1, 256, 0, stream>>>(flags);
  k_scan<<<NWG, 256, 0, stream>>>(WAf, V1tf, Wc1f, WDf,
      ctxV0, gctx, ctx, b1, cb1, cb2, bdg, gb, og, ob,
      hall, hf, h1f, c1f, gcaf, cf, gpre, tfs, flags);

  // ----- lm head -----
  gemmH(stream, hall, 768, lmw, 768, 50257, MR, 50257, 768, nullptr, nullptr,
       out, nullptr, 1.f, 0);
}